// Round 3
// baseline (24.745 us; speedup 1.0000x reference)
//
#include <hip/hip_runtime.h>
#include <math.h>

#define NB   2
#define NSEQ 1024
#define DD   256
#define LUTN 2048   // intervals; LUTN+1 entries over corr in [-1,1]

#define BM 64
#define BN 64
#define BK 32

typedef _Float16 f16;
typedef _Float16 f16x4 __attribute__((ext_vector_type(4)));
typedef _Float16 f16x8 __attribute__((ext_vector_type(8)));
typedef float f32x4 __attribute__((ext_vector_type(4)));

__device__ __forceinline__ float wrsum(float v) {
#pragma unroll
  for (int off = 32; off > 0; off >>= 1) v += __shfl_xor(v, off, 64);
  return v;
}

// Fused: blocks [0,1024) = prep (center rows, f16 hi/lo split, recip norms);
//        blocks [1024,1089) = LUT build.
__global__ __launch_bounds__(256) void prep_lut_kernel(
    const float* __restrict__ fin, const float* __restrict__ sin_,
    const float* __restrict__ w1, const float* __restrict__ b1,
    const float* __restrict__ w2, const float* __restrict__ b2,
    f16* __restrict__ fh, f16* __restrict__ fl,
    f16* __restrict__ sh, f16* __restrict__ sl,
    float* __restrict__ rf, float* __restrict__ rs,
    float* __restrict__ lut) {
  const int b = blockIdx.x;
  const int lane = threadIdx.x & 63;
  const int w = threadIdx.x >> 6;

  if (b < 1024) {
    const int tensor = b >> 9;
    const int row = (b & 511) * 4 + w;  // 0..2047
    const float* src = tensor ? sin_ : fin;
    f16* dh = tensor ? sh : fh;
    f16* dl = tensor ? sl : fl;
    float* dr = tensor ? rs : rf;

    const float4 v = *reinterpret_cast<const float4*>(&src[(size_t)row * DD + lane * 4]);
    const float mean = wrsum(v.x + v.y + v.z + v.w) * (1.0f / DD);
    float c[4] = {v.x - mean, v.y - mean, v.z - mean, v.w - mean};
    const float sq = wrsum(c[0]*c[0] + c[1]*c[1] + c[2]*c[2] + c[3]*c[3]);
    f16x4 hv, lv;
#pragma unroll
    for (int j = 0; j < 4; ++j) {
      f16 h = (f16)c[j];
      hv[j] = h;
      lv[j] = (f16)(c[j] - (float)h);
    }
    *reinterpret_cast<f16x4*>(&dh[(size_t)row * DD + lane * 4]) = hv;
    *reinterpret_cast<f16x4*>(&dl[(size_t)row * DD + lane * 4]) = lv;
    if (lane == 0) dr[row] = 1.0f / fmaxf(sqrtf(sq), 1e-6f);
  } else {
    const int lb = b - 1024;  // 0..64
#pragma unroll
    for (int i = 0; i < 8; ++i) {
      const int e = lb * 32 + w * 8 + i;
      if (e > LUTN) break;
      const float corr = -1.0f + (float)e * (2.0f / LUTN);
      const float a = expf(corr);
      float acc = 0.0f;
#pragma unroll
      for (int h = lane; h < 128; h += 64) {
        const float x = fmaf(a, w1[h], b1[h]);
        const float g = 0.5f * x * (1.0f + erff(x * 0.70710678118654752f));
        acc = fmaf(g, w2[h], acc);
      }
      acc = wrsum(acc);
      if (lane == 0) lut[e] = acc + b2[0];
    }
  }
}

// 64x64 block tile, 4 waves as 2x2 of 32x32, BK=32 double-buffered.
// LDS rows are 128B: [hi 4 slots | lo 4 slots] of 16B, slot ^= row&7 (2-way max).
__global__ __launch_bounds__(256, 2) void gemm_kernel(
    const f16* __restrict__ fh, const f16* __restrict__ fl,
    const f16* __restrict__ sh, const f16* __restrict__ sl,
    const float* __restrict__ rf, const float* __restrict__ rs,
    const float* __restrict__ lut, float* __restrict__ out) {
  __shared__ __align__(16) f16 As[2][BM * 64];   // [buf][row*64 + slot*8 + e]
  __shared__ __align__(16) f16 Bs[2][BN * 64];
  __shared__ float lut_s[LUTN + 1];

  const int t = threadIdx.x;
  const int lane = t & 63;
  const int w = t >> 6;
  const int wr = w >> 1, wc = w & 1;     // 32x32 wave tile at (wr*32, wc*32)
  const int bz = blockIdx.z;
  const int bn0 = blockIdx.x * BN;
  const int bm0 = blockIdx.y * BM;

  const f16* fhb = fh + (size_t)bz * NSEQ * DD;
  const f16* flb = fl + (size_t)bz * NSEQ * DD;
  const f16* shb = sh + (size_t)bz * NSEQ * DD;
  const f16* slb = sl + (size_t)bz * NSEQ * DD;

  for (int i = t; i <= LUTN; i += 256) lut_s[i] = lut[i];

  // staging: thread t owns row r=t>>2, 8-f16 chunk c8=t&3 of each tile/half
  const int sr = t >> 2;
  const int c8 = t & 3;
  f16x8 p_ah, p_al, p_bh, p_bl;

  auto stage_load = [&](int s) {
    const size_t ga = (size_t)(bm0 + sr) * DD + s * BK + c8 * 8;
    const size_t gb = (size_t)(bn0 + sr) * DD + s * BK + c8 * 8;
    p_ah = *reinterpret_cast<const f16x8*>(&fhb[ga]);
    p_al = *reinterpret_cast<const f16x8*>(&flb[ga]);
    p_bh = *reinterpret_cast<const f16x8*>(&shb[gb]);
    p_bl = *reinterpret_cast<const f16x8*>(&slb[gb]);
  };
  auto stage_write = [&](int p) {
    const int oh = sr * 64 + ((c8 ^ (sr & 7)) << 3);
    const int ol = sr * 64 + (((4 + c8) ^ (sr & 7)) << 3);
    *reinterpret_cast<f16x8*>(&As[p][oh]) = p_ah;
    *reinterpret_cast<f16x8*>(&As[p][ol]) = p_al;
    *reinterpret_cast<f16x8*>(&Bs[p][oh]) = p_bh;
    *reinterpret_cast<f16x8*>(&Bs[p][ol]) = p_bl;
  };

  f32x4 acc[2][2] = {};
  const int kslot = lane >> 4;           // 16B slot along K for this lane

  stage_load(0);
  stage_write(0);
  __syncthreads();

  for (int s = 0; s < DD / BK; ++s) {
    const int p = s & 1;
    if (s < DD / BK - 1) stage_load(s + 1);   // issue early; latency hides under MFMA
    f16x8 ah[2], al[2], bh[2], bl[2];
#pragma unroll
    for (int i = 0; i < 2; ++i) {
      const int r = wr * 32 + 16 * i + (lane & 15);
      ah[i] = *reinterpret_cast<const f16x8*>(&As[p][r * 64 + ((kslot ^ (r & 7)) << 3)]);
      al[i] = *reinterpret_cast<const f16x8*>(&As[p][r * 64 + ((((4 + kslot)) ^ (r & 7)) << 3)]);
    }
#pragma unroll
    for (int j = 0; j < 2; ++j) {
      const int r = wc * 32 + 16 * j + (lane & 15);
      bh[j] = *reinterpret_cast<const f16x8*>(&Bs[p][r * 64 + ((kslot ^ (r & 7)) << 3)]);
      bl[j] = *reinterpret_cast<const f16x8*>(&Bs[p][r * 64 + ((((4 + kslot)) ^ (r & 7)) << 3)]);
    }
#pragma unroll
    for (int i = 0; i < 2; ++i)
#pragma unroll
      for (int j = 0; j < 2; ++j) {
        acc[i][j] = __builtin_amdgcn_mfma_f32_16x16x32_f16(ah[i], bh[j], acc[i][j], 0, 0, 0);
        acc[i][j] = __builtin_amdgcn_mfma_f32_16x16x32_f16(ah[i], bl[j], acc[i][j], 0, 0, 0);
        acc[i][j] = __builtin_amdgcn_mfma_f32_16x16x32_f16(al[i], bh[j], acc[i][j], 0, 0, 0);
      }
    if (s < DD / BK - 1) stage_write(p ^ 1);
    __syncthreads();
  }

  // Epilogue: cov -> corr -> clip -> LUT interp -> store.
  const float* rfb = rf + bz * NSEQ;
  const float* rsb = rs + bz * NSEQ;
  float rsv[2];
#pragma unroll
  for (int j = 0; j < 2; ++j) rsv[j] = rsb[bn0 + wc * 32 + 16 * j + (lane & 15)];
#pragma unroll
  for (int i = 0; i < 2; ++i) {
#pragma unroll
    for (int rg = 0; rg < 4; ++rg) {
      const int row = wr * 32 + 16 * i + 4 * (lane >> 4) + rg;
      const float rfv = rfb[bm0 + row];
#pragma unroll
      for (int j = 0; j < 2; ++j) {
        const float cov = acc[i][j][rg] * (1.0f / 16.0f);   // / sqrt(256)
        float corr = fminf(fmaxf(cov * rfv * rsv[j], -1.0f), 1.0f);
        const float tf = (corr + 1.0f) * (float)(LUTN / 2);
        int idx = (int)tf;
        idx = idx > (LUTN - 1) ? (LUTN - 1) : idx;
        const float fr = tf - (float)idx;
        const float lo = lut_s[idx], hi = lut_s[idx + 1];
        out[((size_t)bz * NSEQ + bm0 + row) * NSEQ + bn0 + wc * 32 + 16 * j + (lane & 15)]
            = fmaf(fr, hi - lo, lo);
      }
    }
  }
}

extern "C" void kernel_launch(void* const* d_in, const int* in_sizes, int n_in,
                              void* d_out, int out_size, void* d_ws, size_t ws_size,
                              hipStream_t stream) {
  const float* f  = (const float*)d_in[0];
  const float* s  = (const float*)d_in[1];
  const float* w1 = (const float*)d_in[2];
  const float* b1 = (const float*)d_in[3];
  const float* w2 = (const float*)d_in[4];
  const float* b2 = (const float*)d_in[5];
  float* out = (float*)d_out;

  char* ws = (char*)d_ws;
  const size_t NELEM = (size_t)NB * NSEQ * DD;  // 524288
  f16* fh = (f16*)(ws);
  f16* fl = (f16*)(ws + 2 * NELEM);
  f16* sh = (f16*)(ws + 4 * NELEM);
  f16* sl = (f16*)(ws + 6 * NELEM);
  float* rf  = (float*)(ws + 8 * NELEM);
  float* rs  = (float*)(ws + 8 * NELEM + 8192);
  float* lut = (float*)(ws + 8 * NELEM + 16384);

  prep_lut_kernel<<<1089, 256, 0, stream>>>(f, s, w1, b1, w2, b2,
                                            fh, fl, sh, sl, rf, rs, lut);
  gemm_kernel<<<dim3(NSEQ / BN, NSEQ / BM, NB), 256, 0, stream>>>(
      fh, fl, sh, sl, rf, rs, lut, out);
}

// Round 4
// 24.503 us; speedup vs baseline: 1.0099x; 1.0099x over previous
//
#include <hip/hip_runtime.h>
#include <math.h>

#define NB   2
#define NSEQ 1024
#define DD   256
#define LUTN 2048   // intervals; LUTN+1 entries over corr in [-1,1]

#define BM 64
#define BN 64
#define BK 32

typedef _Float16 f16;
typedef _Float16 f16x4 __attribute__((ext_vector_type(4)));
typedef _Float16 f16x8 __attribute__((ext_vector_type(8)));
typedef float f32x4 __attribute__((ext_vector_type(4)));

__device__ __forceinline__ float wrsum(float v) {
#pragma unroll
  for (int off = 32; off > 0; off >>= 1) v += __shfl_xor(v, off, 64);
  return v;
}

// Fused: blocks [0,1024) = prep (center rows, f16 hi/lo split, recip norms);
//        blocks [1024,1089) = LUT build.
__global__ __launch_bounds__(256) void prep_lut_kernel(
    const float* __restrict__ fin, const float* __restrict__ sin_,
    const float* __restrict__ w1, const float* __restrict__ b1,
    const float* __restrict__ w2, const float* __restrict__ b2,
    f16* __restrict__ fh, f16* __restrict__ fl,
    f16* __restrict__ sh, f16* __restrict__ sl,
    float* __restrict__ rf, float* __restrict__ rs,
    float* __restrict__ lut) {
  const int b = blockIdx.x;
  const int lane = threadIdx.x & 63;
  const int w = threadIdx.x >> 6;

  if (b < 1024) {
    const int tensor = b >> 9;
    const int row = (b & 511) * 4 + w;  // 0..2047
    const float* src = tensor ? sin_ : fin;
    f16* dh = tensor ? sh : fh;
    f16* dl = tensor ? sl : fl;
    float* dr = tensor ? rs : rf;

    const float4 v = *reinterpret_cast<const float4*>(&src[(size_t)row * DD + lane * 4]);
    const float mean = wrsum(v.x + v.y + v.z + v.w) * (1.0f / DD);
    float c[4] = {v.x - mean, v.y - mean, v.z - mean, v.w - mean};
    const float sq = wrsum(c[0]*c[0] + c[1]*c[1] + c[2]*c[2] + c[3]*c[3]);
    f16x4 hv, lv;
#pragma unroll
    for (int j = 0; j < 4; ++j) {
      f16 h = (f16)c[j];
      hv[j] = h;
      lv[j] = (f16)(c[j] - (float)h);
    }
    *reinterpret_cast<f16x4*>(&dh[(size_t)row * DD + lane * 4]) = hv;
    *reinterpret_cast<f16x4*>(&dl[(size_t)row * DD + lane * 4]) = lv;
    if (lane == 0) dr[row] = 1.0f / fmaxf(sqrtf(sq), 1e-6f);
  } else {
    const int lb = b - 1024;  // 0..64
#pragma unroll
    for (int i = 0; i < 8; ++i) {
      const int e = lb * 32 + w * 8 + i;
      if (e > LUTN) break;
      const float corr = -1.0f + (float)e * (2.0f / LUTN);
      const float a = expf(corr);
      float acc = 0.0f;
#pragma unroll
      for (int h = lane; h < 128; h += 64) {
        const float x = fmaf(a, w1[h], b1[h]);
        const float g = 0.5f * x * (1.0f + erff(x * 0.70710678118654752f));
        acc = fmaf(g, w2[h], acc);
      }
      acc = wrsum(acc);
      if (lane == 0) lut[e] = acc + b2[0];
    }
  }
}

// 64x64 block tile, 4 waves as 2x2 of 32x32, BK=32 double-buffered.
// LDS rows are 128B: [hi 4 slots | lo 4 slots] of 16B, slot ^= row&7 (2-way max).
// Grid is flat 512; decoded so XCD (bid&7) owns 4 fixed 64-row F panels and
// streams S: per-XCD L2 working set ~2.25MB < 4MB.
__global__ __launch_bounds__(256, 2) void gemm_kernel(
    const f16* __restrict__ fh, const f16* __restrict__ fl,
    const f16* __restrict__ sh, const f16* __restrict__ sl,
    const float* __restrict__ rf, const float* __restrict__ rs,
    const float* __restrict__ lut, float* __restrict__ out) {
  __shared__ __align__(16) f16 As[2][BM * 64];   // [buf][row*64 + slot*8 + e]
  __shared__ __align__(16) f16 Bs[2][BN * 64];
  __shared__ float lut_s[LUTN + 1];

  const int t = threadIdx.x;
  const int lane = t & 63;
  const int w = t >> 6;
  const int wr = w >> 1, wc = w & 1;     // 32x32 wave tile at (wr*32, wc*32)

  // XCD-aware decode: x = physical XCD (round-robin by bid%8)
  const int bid = blockIdx.x;
  const int x  = bid & 7;
  const int k  = bid >> 3;          // 0..63 within this XCD
  const int pe = k >> 4;            // 0..3: which owned panel
  const int panel_id = x + 8 * pe;  // 0..31
  const int bz  = panel_id >> 4;    // batch
  const int bm0 = (panel_id & 15) * BM;
  const int bn0 = (k & 15) * BN;

  const f16* fhb = fh + (size_t)bz * NSEQ * DD;
  const f16* flb = fl + (size_t)bz * NSEQ * DD;
  const f16* shb = sh + (size_t)bz * NSEQ * DD;
  const f16* slb = sl + (size_t)bz * NSEQ * DD;

  for (int i = t; i <= LUTN; i += 256) lut_s[i] = lut[i];

  // staging: thread t owns row r=t>>2, 8-f16 chunk c8=t&3 of each tile/half
  const int sr = t >> 2;
  const int c8 = t & 3;
  f16x8 p_ah, p_al, p_bh, p_bl;

  auto stage_load = [&](int s) {
    const size_t ga = (size_t)(bm0 + sr) * DD + s * BK + c8 * 8;
    const size_t gb = (size_t)(bn0 + sr) * DD + s * BK + c8 * 8;
    p_ah = *reinterpret_cast<const f16x8*>(&fhb[ga]);
    p_al = *reinterpret_cast<const f16x8*>(&flb[ga]);
    p_bh = *reinterpret_cast<const f16x8*>(&shb[gb]);
    p_bl = *reinterpret_cast<const f16x8*>(&slb[gb]);
  };
  auto stage_write = [&](int p) {
    const int oh = sr * 64 + ((c8 ^ (sr & 7)) << 3);
    const int ol = sr * 64 + (((4 + c8) ^ (sr & 7)) << 3);
    *reinterpret_cast<f16x8*>(&As[p][oh]) = p_ah;
    *reinterpret_cast<f16x8*>(&As[p][ol]) = p_al;
    *reinterpret_cast<f16x8*>(&Bs[p][oh]) = p_bh;
    *reinterpret_cast<f16x8*>(&Bs[p][ol]) = p_bl;
  };

  f32x4 acc[2][2] = {};
  const int kslot = lane >> 4;           // 16B slot along K for this lane

  stage_load(0);
  stage_write(0);
  __syncthreads();

  for (int s = 0; s < DD / BK; ++s) {
    const int p = s & 1;
    if (s < DD / BK - 1) stage_load(s + 1);   // issue early; latency hides under MFMA
    f16x8 ah[2], al[2], bh[2], bl[2];
#pragma unroll
    for (int i = 0; i < 2; ++i) {
      const int r = wr * 32 + 16 * i + (lane & 15);
      ah[i] = *reinterpret_cast<const f16x8*>(&As[p][r * 64 + ((kslot ^ (r & 7)) << 3)]);
      al[i] = *reinterpret_cast<const f16x8*>(&As[p][r * 64 + ((((4 + kslot)) ^ (r & 7)) << 3)]);
    }
#pragma unroll
    for (int j = 0; j < 2; ++j) {
      const int r = wc * 32 + 16 * j + (lane & 15);
      bh[j] = *reinterpret_cast<const f16x8*>(&Bs[p][r * 64 + ((kslot ^ (r & 7)) << 3)]);
      bl[j] = *reinterpret_cast<const f16x8*>(&Bs[p][r * 64 + ((((4 + kslot)) ^ (r & 7)) << 3)]);
    }
#pragma unroll
    for (int i = 0; i < 2; ++i)
#pragma unroll
      for (int j = 0; j < 2; ++j) {
        acc[i][j] = __builtin_amdgcn_mfma_f32_16x16x32_f16(ah[i], bh[j], acc[i][j], 0, 0, 0);
        acc[i][j] = __builtin_amdgcn_mfma_f32_16x16x32_f16(ah[i], bl[j], acc[i][j], 0, 0, 0);
        acc[i][j] = __builtin_amdgcn_mfma_f32_16x16x32_f16(al[i], bh[j], acc[i][j], 0, 0, 0);
      }
    if (s < DD / BK - 1) stage_write(p ^ 1);
    __syncthreads();
  }

  // Epilogue: cov -> corr -> clip -> LUT interp -> store.
  const float* rfb = rf + bz * NSEQ;
  const float* rsb = rs + bz * NSEQ;
  float rsv[2];
#pragma unroll
  for (int j = 0; j < 2; ++j) rsv[j] = rsb[bn0 + wc * 32 + 16 * j + (lane & 15)];
#pragma unroll
  for (int i = 0; i < 2; ++i) {
#pragma unroll
    for (int rg = 0; rg < 4; ++rg) {
      const int row = wr * 32 + 16 * i + 4 * (lane >> 4) + rg;
      const float rfv = rfb[bm0 + row];
#pragma unroll
      for (int j = 0; j < 2; ++j) {
        const float cov = acc[i][j][rg] * (1.0f / 16.0f);   // / sqrt(256)
        float corr = fminf(fmaxf(cov * rfv * rsv[j], -1.0f), 1.0f);
        const float tf = (corr + 1.0f) * (float)(LUTN / 2);
        int idx = (int)tf;
        idx = idx > (LUTN - 1) ? (LUTN - 1) : idx;
        const float fr = tf - (float)idx;
        const float lo = lut_s[idx], hi = lut_s[idx + 1];
        out[((size_t)bz * NSEQ + bm0 + row) * NSEQ + bn0 + wc * 32 + 16 * j + (lane & 15)]
            = fmaf(fr, hi - lo, lo);
      }
    }
  }
}

extern "C" void kernel_launch(void* const* d_in, const int* in_sizes, int n_in,
                              void* d_out, int out_size, void* d_ws, size_t ws_size,
                              hipStream_t stream) {
  const float* f  = (const float*)d_in[0];
  const float* s  = (const float*)d_in[1];
  const float* w1 = (const float*)d_in[2];
  const float* b1 = (const float*)d_in[3];
  const float* w2 = (const float*)d_in[4];
  const float* b2 = (const float*)d_in[5];
  float* out = (float*)d_out;

  char* ws = (char*)d_ws;
  const size_t NELEM = (size_t)NB * NSEQ * DD;  // 524288
  f16* fh = (f16*)(ws);
  f16* fl = (f16*)(ws + 2 * NELEM);
  f16* sh = (f16*)(ws + 4 * NELEM);
  f16* sl = (f16*)(ws + 6 * NELEM);
  float* rf  = (float*)(ws + 8 * NELEM);
  float* rs  = (float*)(ws + 8 * NELEM + 8192);
  float* lut = (float*)(ws + 8 * NELEM + 16384);

  prep_lut_kernel<<<1089, 256, 0, stream>>>(f, s, w1, b1, w2, b2,
                                            fh, fl, sh, sl, rf, rs, lut);
  gemm_kernel<<<512, 256, 0, stream>>>(fh, fl, sh, sl, rf, rs, lut, out);
}

// Round 5
// 24.469 us; speedup vs baseline: 1.0113x; 1.0014x over previous
//
#include <hip/hip_runtime.h>
#include <math.h>

#define NB   2
#define NSEQ 1024
#define DD   256
#define LUTN 2048   // intervals; LUTN+1 entries over corr in [-1,1]

#define BM 128
#define BN 64
#define BK 32

typedef _Float16 f16;
typedef _Float16 f16x8 __attribute__((ext_vector_type(8)));
typedef float f32x4 __attribute__((ext_vector_type(4)));

__device__ __forceinline__ float wrsum(float v) {
#pragma unroll
  for (int off = 32; off > 0; off >>= 1) v += __shfl_xor(v, off, 64);
  return v;
}

// blocks [0,1024): per-row mean + reciprocal centered norm (one wave per row).
// Uses sum-of-squares identity: ||xc||^2 = sum(x^2) - D*mean^2.
// blocks [1024,1089): LUT over corr in [-1,1].
__global__ __launch_bounds__(256) void aux_kernel(
    const float* __restrict__ fin, const float* __restrict__ sin_,
    const float* __restrict__ w1, const float* __restrict__ b1,
    const float* __restrict__ w2, const float* __restrict__ b2,
    float* __restrict__ mf, float* __restrict__ ms,
    float* __restrict__ rf, float* __restrict__ rs,
    float* __restrict__ lut) {
  const int b = blockIdx.x;
  const int lane = threadIdx.x & 63;
  const int w = threadIdx.x >> 6;
  if (b < 1024) {
    const int tensor = b >> 9;
    const int row = (b & 511) * 4 + w;  // 0..2047
    const float* src = tensor ? sin_ : fin;
    const float4 v = *reinterpret_cast<const float4*>(&src[(size_t)row * DD + lane * 4]);
    const float sum = wrsum(v.x + v.y + v.z + v.w);
    const float sq  = wrsum(v.x*v.x + v.y*v.y + v.z*v.z + v.w*v.w);
    if (lane == 0) {
      const float m = sum * (1.0f / DD);
      const float cs = fmaxf(sq - (float)DD * m * m, 0.0f);
      (tensor ? ms : mf)[row] = m;
      (tensor ? rs : rf)[row] = 1.0f / fmaxf(sqrtf(cs), 1e-6f);
    }
  } else {
    const int lb = b - 1024;  // 0..64
#pragma unroll
    for (int i = 0; i < 8; ++i) {
      const int e = lb * 32 + w * 8 + i;
      if (e > LUTN) break;
      const float corr = -1.0f + (float)e * (2.0f / LUTN);
      const float a = expf(corr);
      float acc = 0.0f;
#pragma unroll
      for (int h = lane; h < 128; h += 64) {
        const float xx = fmaf(a, w1[h], b1[h]);
        const float g = 0.5f * xx * (1.0f + erff(xx * 0.70710678118654752f));
        acc = fmaf(g, w2[h], acc);
      }
      acc = wrsum(acc);
      if (lane == 0) lut[e] = acc + b2[0];
    }
  }
}

// Fused raw-GEMM: reads raw fp32 inputs, splits to f16 hi/lo in-register while
// staging to LDS, MFMA (3-term split), epilogue applies rank-1 centering
// correction cov = rawdot - 256*mf*ms, then norm->clip->LUT interp->store.
// 128x64 tile, 4 waves of 64x32, BK=32 dbuf, 56KB LDS -> 2 blocks/CU.
// Grid flat 256 with XCD decode: XCD x owns 2 fixed 128-row panels.
__global__ __launch_bounds__(256) void gemm_kernel(
    const float* __restrict__ fg, const float* __restrict__ sg,
    const float* __restrict__ mf, const float* __restrict__ ms,
    const float* __restrict__ rf, const float* __restrict__ rs,
    const float* __restrict__ lut, float* __restrict__ out) {
  __shared__ __align__(16) f16 As[2][BM * 64];  // row*64: [hi slots 0-3 | lo 4-7], slot ^= row&7
  __shared__ __align__(16) f16 Bs[2][BN * 64];
  __shared__ float lut_s[LUTN + 1];

  const int t = threadIdx.x;
  const int lane = t & 63;
  const int w = t >> 6;
  const int wr = w >> 1, wc = w & 1;       // wave tile 64x32 at (wr*64, wc*32)

  const int bid = blockIdx.x;
  const int x = bid & 7, k = bid >> 3;     // 32 blocks per XCD
  const int panel = x + 8 * (k >> 4);      // 0..15
  const int bz  = panel >> 3;
  const int bm0 = (panel & 7) * BM;
  const int bn0 = (k & 15) * BN;

  const float* fb = fg + ((size_t)bz * NSEQ + bm0) * DD;
  const float* sb = sg + ((size_t)bz * NSEQ + bn0) * DD;

  float4 ra[2][2], rb[2];   // raw staging regs (held across MFMA phase)

  auto stage_load = [&](int st) {
#pragma unroll
    for (int j = 0; j < 2; ++j) {
      const int oi = t + 256 * j;          // octet index: row=oi>>2, oct=oi&3
      const float* p = &fb[(size_t)(oi >> 2) * DD + st * BK + (oi & 3) * 8];
      ra[j][0] = *reinterpret_cast<const float4*>(p);
      ra[j][1] = *reinterpret_cast<const float4*>(p + 4);
    }
    {
      const float* p = &sb[(size_t)(t >> 2) * DD + st * BK + (t & 3) * 8];
      rb[0] = *reinterpret_cast<const float4*>(p);
      rb[1] = *reinterpret_cast<const float4*>(p + 4);
    }
  };

  auto split8 = [](const float4& u0, const float4& u1, f16x8& hv, f16x8& lv) {
    const float vals[8] = {u0.x, u0.y, u0.z, u0.w, u1.x, u1.y, u1.z, u1.w};
#pragma unroll
    for (int e = 0; e < 8; ++e) {
      const f16 h = (f16)vals[e];
      hv[e] = h;
      lv[e] = (f16)(vals[e] - (float)h);
    }
  };

  auto cvt_write = [&](int pbuf) {
#pragma unroll
    for (int j = 0; j < 2; ++j) {
      const int oi = t + 256 * j;
      const int r = oi >> 2, o = oi & 3;
      f16x8 hv, lv;
      split8(ra[j][0], ra[j][1], hv, lv);
      *reinterpret_cast<f16x8*>(&As[pbuf][r * 64 + ((o ^ (r & 7)) << 3)]) = hv;
      *reinterpret_cast<f16x8*>(&As[pbuf][r * 64 + (((4 + o) ^ (r & 7)) << 3)]) = lv;
    }
    {
      const int r = t >> 2, o = t & 3;
      f16x8 hv, lv;
      split8(rb[0], rb[1], hv, lv);
      *reinterpret_cast<f16x8*>(&Bs[pbuf][r * 64 + ((o ^ (r & 7)) << 3)]) = hv;
      *reinterpret_cast<f16x8*>(&Bs[pbuf][r * 64 + (((4 + o) ^ (r & 7)) << 3)]) = lv;
    }
  };

  f32x4 acc[4][2] = {};
  const int kslot = lane >> 4;

  stage_load(0);                                        // issue first: hide HBM latency
  for (int i = t; i <= LUTN; i += 256) lut_s[i] = lut[i];
  cvt_write(0);
  __syncthreads();

  for (int st = 0; st < DD / BK; ++st) {
    const int p = st & 1;
    if (st < DD / BK - 1) stage_load(st + 1);           // prefetch next raw tile
    f16x8 ah[4], al[4], bh[2], bl[2];
#pragma unroll
    for (int i = 0; i < 4; ++i) {
      const int r = wr * 64 + 16 * i + (lane & 15);
      ah[i] = *reinterpret_cast<const f16x8*>(&As[p][r * 64 + ((kslot ^ (r & 7)) << 3)]);
      al[i] = *reinterpret_cast<const f16x8*>(&As[p][r * 64 + (((4 + kslot) ^ (r & 7)) << 3)]);
    }
#pragma unroll
    for (int j = 0; j < 2; ++j) {
      const int r = wc * 32 + 16 * j + (lane & 15);
      bh[j] = *reinterpret_cast<const f16x8*>(&Bs[p][r * 64 + ((kslot ^ (r & 7)) << 3)]);
      bl[j] = *reinterpret_cast<const f16x8*>(&Bs[p][r * 64 + (((4 + kslot) ^ (r & 7)) << 3)]);
    }
#pragma unroll
    for (int i = 0; i < 4; ++i)
#pragma unroll
      for (int j = 0; j < 2; ++j) {
        acc[i][j] = __builtin_amdgcn_mfma_f32_16x16x32_f16(ah[i], bh[j], acc[i][j], 0, 0, 0);
        acc[i][j] = __builtin_amdgcn_mfma_f32_16x16x32_f16(ah[i], bl[j], acc[i][j], 0, 0, 0);
        acc[i][j] = __builtin_amdgcn_mfma_f32_16x16x32_f16(al[i], bh[j], acc[i][j], 0, 0, 0);
      }
    if (st < DD / BK - 1) cvt_write(p ^ 1);
    __syncthreads();
  }

  // Epilogue: rank-1 centering correction -> corr -> clip -> LUT -> store.
  const float* mfb = mf + bz * NSEQ;
  const float* msb = ms + bz * NSEQ;
  const float* rfb = rf + bz * NSEQ;
  const float* rsb = rs + bz * NSEQ;
  float msv[2], rsv[2];
#pragma unroll
  for (int j = 0; j < 2; ++j) {
    const int col = bn0 + wc * 32 + 16 * j + (lane & 15);
    msv[j] = msb[col];
    rsv[j] = rsb[col];
  }
#pragma unroll
  for (int i = 0; i < 4; ++i) {
#pragma unroll
    for (int rg = 0; rg < 4; ++rg) {
      const int row = wr * 64 + 16 * i + 4 * (lane >> 4) + rg;
      const float mfv = mfb[bm0 + row];
      const float rfv = rfb[bm0 + row];
#pragma unroll
      for (int j = 0; j < 2; ++j) {
        // cov_centered/16 = rawdot/16 - 16*mf*ms   (256/16 = 16)
        const float cov = acc[i][j][rg] * (1.0f / 16.0f) - 16.0f * mfv * msv[j];
        float corr = fminf(fmaxf(cov * rfv * rsv[j], -1.0f), 1.0f);
        const float tf = (corr + 1.0f) * (float)(LUTN / 2);
        int idx = (int)tf;
        idx = idx > (LUTN - 1) ? (LUTN - 1) : idx;
        const float fr = tf - (float)idx;
        const float lo = lut_s[idx], hi = lut_s[idx + 1];
        out[((size_t)bz * NSEQ + bm0 + row) * NSEQ + bn0 + wc * 32 + 16 * j + (lane & 15)]
            = fmaf(fr, hi - lo, lo);
      }
    }
  }
}

extern "C" void kernel_launch(void* const* d_in, const int* in_sizes, int n_in,
                              void* d_out, int out_size, void* d_ws, size_t ws_size,
                              hipStream_t stream) {
  const float* f  = (const float*)d_in[0];
  const float* s  = (const float*)d_in[1];
  const float* w1 = (const float*)d_in[2];
  const float* b1 = (const float*)d_in[3];
  const float* w2 = (const float*)d_in[4];
  const float* b2 = (const float*)d_in[5];
  float* out = (float*)d_out;

  char* ws = (char*)d_ws;
  float* mf  = (float*)(ws);            // 2048 floats
  float* ms  = (float*)(ws + 8192);
  float* rf  = (float*)(ws + 16384);
  float* rs  = (float*)(ws + 24576);
  float* lut = (float*)(ws + 32768);    // LUTN+1 floats

  aux_kernel<<<1089, 256, 0, stream>>>(f, s, w1, b1, w2, b2, mf, ms, rf, rs, lut);
  gemm_kernel<<<256, 256, 0, stream>>>(f, s, mf, ms, rf, rs, lut, out);
}